// Round 2
// baseline (371.632 us; speedup 1.0000x reference)
//
#include <hip/hip_runtime.h>
#include <cstdint>
#include <cstddef>
#include <cmath>

typedef __bf16 bf16_t;
typedef __bf16 bf16x8 __attribute__((ext_vector_type(8)));
typedef float floatx4 __attribute__((ext_vector_type(4)));

#define AS1 __attribute__((address_space(1)))
#define AS3 __attribute__((address_space(3)))

__device__ __forceinline__ void gload_lds16(const bf16_t* g, bf16_t* l) {
    __builtin_amdgcn_global_load_lds((AS1 void*)(uintptr_t)(g), (AS3 void*)(l), 16, 0, 0);
}

__device__ __forceinline__ float sigf(float x) { return 1.0f / (1.0f + __expf(-x)); }
__device__ __forceinline__ float tanhfast(float x) { return 1.0f - 2.0f / (__expf(2.0f * x) + 1.0f); }

// ==================== 8-phase 256x256 fused GEMM+LSTM (encoder) ====================
// gates(M x N) = A(M,K) @ W(N,K)^T + bias(N), LSTM cell fused in epilogue.
// T3+T4+T5 port of the 256^2 8-phase template: BK=64 split in 32-K halves;
// LDS = 4-slot ring per operand (slot = 16KB = 256 rows x 32 K bf16), staged
// 5-6 phases ahead of consumption; counted vmcnt(8) only at the end of phases
// 2/4 of each K-tile, placed BEFORE the barrier so slot completion is
// confirmed across all waves (vmcnt is per-wave; the following s_barrier
// makes each wave's confirmation visible to readers in the next phase).
// Swizzle (rule #21, both-sides): slot rows are 4 chunks of 16B; phys chunk
// = logical ^ ((row>>1)&3), applied on the per-lane GLOBAL source address
// (LDS dest stays linear base+lane*16 as global_load_lds requires) and on
// the ds_read side. 16-lane fragment reads then cover all 8 bank-groups
// 2-way (free). 8 waves (2M x 4N), per-wave output 128x64; the 4 N-frags of
// a wave are the 4 gates (i,f,g,o) of element e = ((n0+wn)>>2)+(lane&15).
__global__ __launch_bounds__(512, 2)
void gemm_lstm8(const bf16_t* __restrict__ A, const bf16_t* __restrict__ Bw,
                const float* __restrict__ bias, float* __restrict__ c, int EP,
                bf16_t* __restrict__ hb, int ldH, int hoff, float* __restrict__ hf,
                int K, int ldA, int ldB, int relu, int czero)
{
    __shared__ bf16_t As[4 * 8192];   // 4 slots x 256 rows x 32 K = 64 KB
    __shared__ bf16_t Bs[4 * 8192];   // 64 KB
    const int tid  = threadIdx.x;
    const int lane = tid & 63;
    const int w    = tid >> 6;
    const int wm   = (w & 1) * 128;
    const int wn   = (w >> 1) * 64;

    // XCD-aware bijective swizzle: 256 blocks, 8 XCDs -> 32 consecutive
    // tiles per XCD (2 full B-panel columns stay hot in that XCD's L2).
    const int bid = blockIdx.x;
    const int swz = (bid & 7) * 32 + (bid >> 3);
    const int m0  = (swz & 15) * 256;
    const int n0  = (swz >> 4) * 256;

    const int NT = K >> 6;            // K-tiles of 64 (K is a multiple of 64, NT>=2)

    // ---- staging side: thread stages chunk q=tid and q=tid+512 of a slot ----
    // chunk q -> row = q>>2, phys chunk pc = q&3, logical chunk lc = pc ^ ((row>>1)&3)
    const int srow = tid >> 2;                       // 0..127 (round 2: +128)
    const int slc  = (tid & 3) ^ ((tid >> 3) & 3);   // logical k-chunk for this thread
    const bf16_t* Asrc0 = A  + (size_t)(m0 + srow) * ldA + slc * 8;
    const bf16_t* Asrc1 = Asrc0 + (size_t)128 * ldA;
    const bf16_t* Bsrc0 = Bw + (size_t)(n0 + srow) * ldB + slc * 8;
    const bf16_t* Bsrc1 = Bsrc0 + (size_t)128 * ldB;
    bf16_t* AsD = As + tid * 8;                      // linear LDS dest (+slot*8192)
    bf16_t* BsD = Bs + tid * 8;

    // ---- read side: frag row R = base + fr, logical chunk lq = lane>>4 ----
    // phys chunk = lq ^ ((R>>1)&3) = lq ^ ((fr>>1)&3)  (bases are mult. of 16)
    const int fr    = lane & 15;
    const int rdoff = fr * 32 + (((lane >> 4) ^ ((fr >> 1) & 3)) * 8);

    floatx4 zero = {0.0f, 0.0f, 0.0f, 0.0f};
    floatx4 acc[8][4];
#pragma unroll
    for (int i = 0; i < 8; ++i)
#pragma unroll
        for (int j = 0; j < 4; ++j) acc[i][j] = zero;
    bf16x8 af[4], bfr[4];

#define STAGE_A8(slot, koff) { gload_lds16(Asrc0 + (koff), AsD + (slot) * 8192); \
                               gload_lds16(Asrc1 + (koff), AsD + (slot) * 8192 + 4096); }
#define STAGE_B8(slot, koff) { gload_lds16(Bsrc0 + (koff), BsD + (slot) * 8192); \
                               gload_lds16(Bsrc1 + (koff), BsD + (slot) * 8192 + 4096); }
#define RD_B8(slot) { _Pragma("unroll") for (int j = 0; j < 4; ++j) \
    bfr[j] = *(const bf16x8*)(Bs + (slot) * 8192 + (wn + j * 16) * 32 + rdoff); }
#define RD_A8(slot, ib) { _Pragma("unroll") for (int ii = 0; ii < 4; ++ii) \
    af[ii] = *(const bf16x8*)(As + (slot) * 8192 + (wm + ((ib) + ii) * 16) * 32 + rdoff); }
#define MF8(ib) { __builtin_amdgcn_s_setprio(1); \
    _Pragma("unroll") for (int ii = 0; ii < 4; ++ii) \
    _Pragma("unroll") for (int j = 0; j < 4; ++j) \
        acc[(ib) + ii][j] = __builtin_amdgcn_mfma_f32_16x16x32_bf16(af[ii], bfr[j], acc[(ib) + ii][j], 0, 0, 0); \
    __builtin_amdgcn_s_setprio(0); }
#define BAR8()  __builtin_amdgcn_s_barrier()
#define LGKM0() asm volatile("s_waitcnt lgkmcnt(0)" ::: "memory")

    // ---- prologue: stage 6 slots (tiles 0 and 1-h0), confirm first tile-0 pair ----
    STAGE_A8(0, 0);  STAGE_B8(0, 0);     // A/B(0,h0)
    STAGE_A8(1, 32); STAGE_B8(1, 32);    // A/B(0,h1)
    STAGE_A8(2, 64); STAGE_B8(2, 64);    // A/B(1,h0)
    asm volatile("s_waitcnt vmcnt(8)" ::: "memory");  // A/B(0,h0) landed
    BAR8();

    // Phase layout per K-tile t (slots sA0=(2t)&3 h0, sA1=(2t+1)&3 h1):
    //  ph0: rdB(sA0)+rdA(sA0,mh0) | stage A(t+1,h1)->(2t+3)&3 | bar lgkm mfma bar
    //  ph1: rdA(sA0,mh1)          | stage B(t+1,h1)           | bar lgkm mfma vmcnt(8) bar
    //  ph2: rdB(sA1)+rdA(sA1,mh0) | stage A(t+2,h0)->sA0      | bar lgkm mfma bar
    //  ph3: rdA(sA1,mh1)          | stage B(t+2,h0)           | bar lgkm mfma vmcnt(8) bar
    // The vmcnt before the barrier confirms the slots needed 1 phase later.
#define TILE8(t, doS01, doS23, VM1, VM3)                                   \
  { const int sA0 = (2 * (t)) & 3, sA1 = (2 * (t) + 1) & 3;                \
    const int sN  = (2 * (t) + 3) & 3;                                     \
    const int kN1 = ((t) + 1) * 64 + 32, kN2 = ((t) + 2) * 64;             \
    RD_B8(sA0); RD_A8(sA0, 0);                                             \
    if (doS01) STAGE_A8(sN, kN1);                                          \
    BAR8(); LGKM0(); MF8(0); BAR8();                                       \
    RD_A8(sA0, 4);                                                         \
    if (doS01) STAGE_B8(sN, kN1);                                          \
    BAR8(); LGKM0(); MF8(4);                                               \
    asm volatile("s_waitcnt " VM1 ::: "memory"); BAR8();                   \
    RD_B8(sA1); RD_A8(sA1, 0);                                             \
    if (doS23) STAGE_A8(sA0, kN2);                                         \
    BAR8(); LGKM0(); MF8(0); BAR8();                                       \
    RD_A8(sA1, 4);                                                         \
    if (doS23) STAGE_B8(sA0, kN2);                                         \
    BAR8(); LGKM0(); MF8(4);                                               \
    asm volatile("s_waitcnt " VM3 ::: "memory"); BAR8(); }

    for (int t = 0; t + 2 < NT; ++t)
        TILE8(t, 1, 1, "vmcnt(8)", "vmcnt(8)");
    TILE8(NT - 2, 1, 0, "vmcnt(8)", "vmcnt(4)");   // stage only A/B(NT-1,h1)
    TILE8(NT - 1, 0, 0, "vmcnt(0)", "vmcnt(0)");   // no staging, drain

    // ---- fused LSTM epilogue. C/D: col = lane&15, row = (lane>>4)*4 + reg ----
    const int crow = (lane >> 4) * 4;
    const int ccol = lane & 15;
    const int e    = ((n0 + wn) >> 2) + ccol;
    float bi[4];
#pragma unroll
    for (int j = 0; j < 4; ++j) bi[j] = bias[n0 + wn + j * 16 + ccol];

#pragma unroll
    for (int i = 0; i < 8; ++i) {
#pragma unroll
        for (int r = 0; r < 4; ++r) {
            int t = m0 + wm + i * 16 + crow + r;
            float iv = acc[i][0][r] + bi[0];
            float fv = acc[i][1][r] + bi[1];
            float gv = acc[i][2][r] + bi[2];
            float ov = acc[i][3][r] + bi[3];
            size_t cix = (size_t)t * EP + e;
            float cold = 0.0f;
            if (!czero) cold = c[cix];
            float cv = sigf(fv) * cold + sigf(iv) * tanhfast(gv);
            c[cix] = cv;
            float hv = sigf(ov) * tanhfast(cv);
            if (relu) hv = fmaxf(hv, 0.0f);
            if (hb) hb[(size_t)t * ldH + hoff + e] = (bf16_t)hv;
            else    hf[(size_t)t * EP + e] = hv;
        }
    }
}

// ------------- 2-barrier fused GEMM+LSTM (decoder; N=512 -> small tiles) -------------
template<int BM>
__global__ __launch_bounds__(256, 4)
void gemm_lstm(const bf16_t* __restrict__ A, const bf16_t* __restrict__ B,
               const float* __restrict__ bias, float* __restrict__ c, int EP,
               bf16_t* __restrict__ hb, int ldH, int hoff, float* __restrict__ hf,
               int K, int ldA, int ldB, int relu, int czero)
{
    constexpr int AI = BM / 32;          // i-frags per wave = A-chunks per thread
    __shared__ bf16_t As[BM * 64];
    __shared__ bf16_t Bs[128 * 64];
    const int tid  = threadIdx.x;
    const int lane = tid & 63;
    const int w    = tid >> 6;
    const int wm   = (w & 1) * (BM / 2);
    const int wn   = (w >> 1) * 64;
    const int m0   = blockIdx.y * BM;
    const int n0   = blockIdx.x * 128;

    floatx4 zero = {0.0f, 0.0f, 0.0f, 0.0f};
    floatx4 acc[AI][4];
#pragma unroll
    for (int i = 0; i < AI; ++i)
#pragma unroll
        for (int j = 0; j < 4; ++j) acc[i][j] = zero;

    const int srow = lane >> 3;                 // staging row-in-chunk 0..7
    const int sk   = ((lane & 7) ^ srow) * 8;   // swizzled k-chunk (elements)
    const int fr   = lane & 15;                 // fragment row
    const int fx   = fr & 7;                    // read-side xor key

    const bf16_t* Ag = A + (size_t)(m0 + srow) * ldA + sk;
    const bf16_t* Bg = B + (size_t)(n0 + srow) * ldB + sk;

    for (int k0 = 0; k0 < K; k0 += 64) {
        __syncthreads();
#pragma unroll
        for (int j = 0; j < AI; ++j) {
            int r0 = (w * AI + j) * 8;
            gload_lds16(Ag + (size_t)r0 * ldA + k0, As + r0 * 64 + lane * 8);
        }
#pragma unroll
        for (int j = 0; j < 4; ++j) {
            int r0 = (w * 4 + j) * 8;
            gload_lds16(Bg + (size_t)r0 * ldB + k0, Bs + r0 * 64 + lane * 8);
        }
        __syncthreads();
#pragma unroll
        for (int kk = 0; kk < 64; kk += 32) {
            const int pc = ((((kk >> 3) + (lane >> 4)) ^ fx) << 3);
            bf16x8 af[AI], bfr[4];
#pragma unroll
            for (int i = 0; i < AI; ++i)
                af[i] = *(const bf16x8*)(As + (wm + i * 16 + fr) * 64 + pc);
#pragma unroll
            for (int j = 0; j < 4; ++j)
                bfr[j] = *(const bf16x8*)(Bs + (wn + j * 16 + fr) * 64 + pc);
#pragma unroll
            for (int i = 0; i < AI; ++i)
#pragma unroll
                for (int j = 0; j < 4; ++j)
                    acc[i][j] = __builtin_amdgcn_mfma_f32_16x16x32_bf16(af[i], bfr[j], acc[i][j], 0, 0, 0);
        }
    }

    const int crow = (lane >> 4) * 4;
    const int ccol = lane & 15;
    const int e    = ((n0 + wn) >> 2) + ccol;
    float bi[4];
#pragma unroll
    for (int j = 0; j < 4; ++j) bi[j] = bias[n0 + wn + j * 16 + ccol];

#pragma unroll
    for (int i = 0; i < AI; ++i) {
#pragma unroll
        for (int r = 0; r < 4; ++r) {
            int t = m0 + wm + i * 16 + crow + r;
            float iv = acc[i][0][r] + bi[0];
            float fv = acc[i][1][r] + bi[1];
            float gv = acc[i][2][r] + bi[2];
            float ov = acc[i][3][r] + bi[3];
            size_t cix = (size_t)t * EP + e;
            float cold = 0.0f;
            if (!czero) cold = c[cix];
            float cv = sigf(fv) * cold + sigf(iv) * tanhfast(gv);
            c[cix] = cv;
            float hv = sigf(ov) * tanhfast(cv);
            if (relu) hv = fmaxf(hv, 0.0f);
            if (hb) hb[(size_t)t * ldH + hoff + e] = (bf16_t)hv;
            else    hf[(size_t)t * EP + e] = hv;
        }
    }
}

// ---------------- Packing (interleaved-gate layout, vectorized) ----------------
// A_enc (4096 x 1152 bf16): [x(0:101) pad(101:128) h(128:1152)]
// A_dec (4096 x 1152 bf16): [enc(0:1024) h(1024:1152)]
// One kernel, block-range dispatched (all outputs disjoint):
//   [0,     9216) : W_enc  (16384 rows * 144 groups of 8)
//   [9216, 11520) : A_enc x+zero fill (4096 rows * 144 groups)
//   [11520,12672) : W_dec  (2048 rows * 144 groups)
//   [12672,12744) : biases (16384 enc + 2048 dec)
// Layer-0 K-trim + czero keep every other buffer write-before-read
// (ws re-poisoned 0xAA every call).
__global__ void pack_all(const float* __restrict__ x,
                         const float* __restrict__ eWih, const float* __restrict__ eWhh,
                         const float* __restrict__ ebih, const float* __restrict__ ebhh,
                         const float* __restrict__ dWih, const float* __restrict__ dWhh,
                         const float* __restrict__ dbih, const float* __restrict__ dbhh,
                         bf16_t* __restrict__ Aenc, bf16_t* __restrict__ Wenc,
                         bf16_t* __restrict__ Wdec,
                         float* __restrict__ bse, float* __restrict__ bsd)
{
    const int b = blockIdx.x;
    if (b < 9216) {
        int gid = b * 256 + threadIdx.x;
        int row = gid / 144, grp = gid - row * 144;
        int l = row >> 12, p = row & 4095;
        int g = (p >> 4) & 3, e = ((p >> 6) << 4) + (p & 15);
        int c0 = grp * 8;
        float v[8];
#pragma unroll
        for (int u = 0; u < 8; ++u) v[u] = 0.0f;
        if (e < 1000) {
            size_t r = (size_t)l * 4000 + g * 1000 + e;
            if (c0 >= 128 && c0 < 1128) {
                const float* src = eWhh + r * 1000 + (c0 - 128);
                float4 a = *(const float4*)src;
                float4 bq = *(const float4*)(src + 4);
                v[0]=a.x; v[1]=a.y; v[2]=a.z; v[3]=a.w; v[4]=bq.x; v[5]=bq.y; v[6]=bq.z; v[7]=bq.w;
            } else if (c0 < 128) {
                const float* src = eWih + r * 101;
#pragma unroll
                for (int u = 0; u < 8; ++u) { int cc = c0 + u; if (cc < 101) v[u] = src[cc]; }
            }
        }
        bf16x8 o;
#pragma unroll
        for (int u = 0; u < 8; ++u) o[u] = (bf16_t)v[u];
        *(bf16x8*)(Wenc + (size_t)row * 1152 + c0) = o;
    } else if (b < 11520) {
        int gid = (b - 9216) * 256 + threadIdx.x;
        int row = gid / 144, grp = gid - row * 144;
        int c0  = grp * 8;
        float v[8];
#pragma unroll
        for (int u = 0; u < 8; ++u) v[u] = 0.0f;
        if (c0 < 101) {
            const float* src = x + (size_t)row * 101;
#pragma unroll
            for (int u = 0; u < 8; ++u) { int cc = c0 + u; if (cc < 101) v[u] = src[cc]; }
        }
        bf16x8 o;
#pragma unroll
        for (int u = 0; u < 8; ++u) o[u] = (bf16_t)v[u];
        *(bf16x8*)(Aenc + (size_t)row * 1152 + c0) = o;
    } else if (b < 12672) {
        int gid = (b - 11520) * 256 + threadIdx.x;
        int row = gid / 144, grp = gid - row * 144;
        int l = row >> 9, p = row & 511;
        int g = (p >> 4) & 3, e = ((p >> 6) << 4) + (p & 15);
        int c0 = grp * 8;
        float v[8];
#pragma unroll
        for (int u = 0; u < 8; ++u) v[u] = 0.0f;
        if (e < 101) {
            size_t r = (size_t)l * 404 + g * 101 + e;
            if (c0 < 1000) {
                const float* src = dWih + r * 1000 + c0;
                float4 a = *(const float4*)src;
                float4 bq = *(const float4*)(src + 4);
                v[0]=a.x; v[1]=a.y; v[2]=a.z; v[3]=a.w; v[4]=bq.x; v[5]=bq.y; v[6]=bq.z; v[7]=bq.w;
            } else if (c0 >= 1024 && c0 < 1128) {
                const float* src = dWhh + r * 101;
#pragma unroll
                for (int u = 0; u < 8; ++u) { int cc = c0 + u; if (cc < 1125) v[u] = src[cc - 1024]; }
            }
        }
        bf16x8 o;
#pragma unroll
        for (int u = 0; u < 8; ++u) o[u] = (bf16_t)v[u];
        *(bf16x8*)(Wdec + (size_t)row * 1152 + c0) = o;
    } else {
        int idx = (b - 12672) * 256 + threadIdx.x;
        if (idx < 16384) {
            int l = idx >> 12, p = idx & 4095;
            int g = (p >> 4) & 3, e = ((p >> 6) << 4) + (p & 15);
            bse[idx] = (e < 1000) ? (ebih[l * 4000 + g * 1000 + e] + ebhh[l * 4000 + g * 1000 + e]) : 0.0f;
        } else {
            int k = idx - 16384;
            int l = k >> 9, p = k & 511;
            int g = (p >> 4) & 3, e = ((p >> 6) << 4) + (p & 15);
            bsd[k] = (e < 101) ? (dbih[l * 404 + g * 101 + e] + dbhh[l * 404 + g * 101 + e]) : 0.0f;
        }
    }
}

// ---------------- log_softmax over 101 valid cols (stride 128) ----------------
__global__ void log_softmax_k(const float* __restrict__ h, float* __restrict__ out)
{
    int row = blockIdx.x;
    int l   = threadIdx.x;          // 64
    const float* hr = h + (size_t)row * 128;
    float v1 = (l < 101)      ? hr[l]      : -INFINITY;
    float v2 = (l + 64 < 101) ? hr[l + 64] : -INFINITY;
    float m = fmaxf(v1, v2);
#pragma unroll
    for (int off = 32; off > 0; off >>= 1) m = fmaxf(m, __shfl_down(m, off));
    m = __shfl(m, 0);
    float ev = ((l < 101) ? __expf(v1 - m) : 0.0f) + ((l + 64 < 101) ? __expf(v2 - m) : 0.0f);
#pragma unroll
    for (int off = 32; off > 0; off >>= 1) ev += __shfl_down(ev, off);
    float lse = m + __logf(__shfl(ev, 0));
    float* orow = out + (size_t)row * 101;
    if (l < 101)      orow[l]      = v1 - lse;
    if (l + 64 < 101) orow[l + 64] = v2 - lse;
}

extern "C" void kernel_launch(void* const* d_in, const int* in_sizes, int n_in,
                              void* d_out, int out_size, void* d_ws, size_t ws_size,
                              hipStream_t stream)
{
    (void)in_sizes; (void)n_in; (void)out_size; (void)ws_size;
    const float* x    = (const float*)d_in[0];
    const float* eWih = (const float*)d_in[1];
    const float* eWhh = (const float*)d_in[2];
    const float* ebih = (const float*)d_in[3];
    const float* ebhh = (const float*)d_in[4];
    const float* dWih = (const float*)d_in[5];
    const float* dWhh = (const float*)d_in[6];
    const float* dbih = (const float*)d_in[7];
    const float* dbhh = (const float*)d_in[8];

    char* ws = (char*)d_ws;
    bf16_t* Aenc = (bf16_t*)(ws);                 // 4096*1152*2   =  9,437,184
    bf16_t* Wenc = (bf16_t*)(ws + 9437184);       // 4*4096*1152*2 = 37,748,736
    bf16_t* Adec = (bf16_t*)(ws + 47185920);      //                  9,437,184
    bf16_t* Wdec = (bf16_t*)(ws + 56623104);      // 4*512*1152*2  =  4,718,592
    float*  bse  = (float*) (ws + 61341696);      // 4*4096*4      =     65,536
    float*  bsd  = (float*) (ws + 61407232);      // 4*512*4       =      8,192
    float*  cenc = (float*) (ws + 61415424);      // 4096*1024*4   = 16,777,216
    float*  cdec = (float*) (ws + 78192640);      // 4096*128*4    =   2,097,152
    float*  hdec = (float*) (ws + 80289792);      // 4096*128*4    =   2,097,152  (end 82,386,944)

    pack_all<<<12744, 256, 0, stream>>>(x, eWih, eWhh, ebih, ebhh, dWih, dWhh, dbih, dbhh,
                                        Aenc, Wenc, Wdec, bse, bsd);

    // Encoder: 4 layers on the 8-phase 256^2 kernel (grid 256 = 1 block/CU).
    // Layer 0: h == 0 -> K=128 (x part only), czero=1 (c-in exactly zero).
    for (int l = 0; l < 4; ++l) {
        gemm_lstm8<<<256, 512, 0, stream>>>(
            Aenc, Wenc + (size_t)l * 4096 * 1152, bse + l * 4096,
            cenc, 1024,
            (l < 3) ? Aenc : Adec, 1152, (l < 3) ? 128 : 0, nullptr,
            (l == 0) ? 128 : 1152, 1152, 1152, (l == 3) ? 1 : 0, (l == 0) ? 1 : 0);
    }
    // Decoder: 4 layers. BM=32 -> grid(4,128)=512 blocks = 2 blocks/CU.
    // Layer 0: h == 0 -> K=1024 (enc part only), czero=1.
    for (int l = 0; l < 4; ++l) {
        gemm_lstm<32><<<dim3(4, 128), 256, 0, stream>>>(
            Adec, Wdec + (size_t)l * 512 * 1152, bsd + l * 512,
            cdec, 128,
            (l < 3) ? Adec : nullptr, 1152, 1024, (l == 3) ? hdec : nullptr,
            (l == 0) ? 1024 : 1152, 1152, 1152, 0, (l == 0) ? 1 : 0);
    }
    log_softmax_k<<<4096, 64, 0, stream>>>(hdec, (float*)d_out);
}

// Round 3
// 339.258 us; speedup vs baseline: 1.0954x; 1.0954x over previous
//
#include <hip/hip_runtime.h>
#include <cstdint>
#include <cstddef>
#include <cmath>

typedef __bf16 bf16_t;
typedef __bf16 bf16x8 __attribute__((ext_vector_type(8)));
typedef float floatx4 __attribute__((ext_vector_type(4)));

#define AS1 __attribute__((address_space(1)))
#define AS3 __attribute__((address_space(3)))

__device__ __forceinline__ void gload_lds16(const bf16_t* g, bf16_t* l) {
    __builtin_amdgcn_global_load_lds((AS1 void*)(uintptr_t)(g), (AS3 void*)(l), 16, 0, 0);
}

__device__ __forceinline__ float sigf(float x) { return 1.0f / (1.0f + __expf(-x)); }
__device__ __forceinline__ float tanhfast(float x) { return 1.0f - 2.0f / (__expf(2.0f * x) + 1.0f); }

// ------------- Fused GEMM + LSTM cell (templated M-tile) -------------
// gates(M x N) = A(M,K) @ W(N,K)^T + bias(N), then LSTM cell per element.
// Weight rows packed gate-interleaved: each lane's acc[i][0..3] are the 4
// gates (i,f,g,o) of one element column e = ((n0+wn)>>2)+(lane&15).
// LDS XOR swizzle: physical 16B chunk = logical_kchunk ^ (row&7); staging
// keeps the mandatory linear base+lane*16 global_load_lds pattern by
// permuting the per-lane *global* address (still intra-128B-segment coalesced).
// This is the proven 2-barrier m97-structure (51 us/enc-layer, 4 blocks/CU);
// the R2 8-phase experiment regressed (19% MfmaUtil, lockstep waves) and is
// reverted.
// Modes:
//   zout != 0 : pure GEMM+bias, write f32 gates to zout (row stride ldZ), no cell.
//   zp   != 0 : cell path, but gate base comes from zp (precomputed gates incl.
//               bias) instead of bias.
//   czero = 1 : c-in is exactly zero -> skip the c load (layer 0).
//   K = 0     : skip the GEMM loop entirely (acc = 0); used for dec layer 0
//               where gates == Z_0.
template<int BM>
__global__ __launch_bounds__(256, 4)
void gemm_lstm(const bf16_t* __restrict__ A, const bf16_t* __restrict__ B,
               const float* __restrict__ bias,
               const float* __restrict__ zp, float* __restrict__ zout, int ldZ,
               float* __restrict__ c, int EP,
               bf16_t* __restrict__ hb, int ldH, int hoff, float* __restrict__ hf,
               int K, int ldA, int ldB, int relu, int czero)
{
    constexpr int AI = BM / 32;          // i-frags per wave = A-chunks per thread
    __shared__ bf16_t As[BM * 64];
    __shared__ bf16_t Bs[128 * 64];
    const int tid  = threadIdx.x;
    const int lane = tid & 63;
    const int w    = tid >> 6;
    const int wm   = (w & 1) * (BM / 2);
    const int wn   = (w >> 1) * 64;
    const int m0   = blockIdx.y * BM;
    const int n0   = blockIdx.x * 128;

    floatx4 zero = {0.0f, 0.0f, 0.0f, 0.0f};
    floatx4 acc[AI][4];
#pragma unroll
    for (int i = 0; i < AI; ++i)
#pragma unroll
        for (int j = 0; j < 4; ++j) acc[i][j] = zero;

    const int srow = lane >> 3;                 // staging row-in-chunk 0..7
    const int sk   = ((lane & 7) ^ srow) * 8;   // swizzled k-chunk (elements)
    const int fr   = lane & 15;                 // fragment row
    const int fx   = fr & 7;                    // read-side xor key

    const bf16_t* Ag = A + (size_t)(m0 + srow) * ldA + sk;
    const bf16_t* Bg = B + (size_t)(n0 + srow) * ldB + sk;

    for (int k0 = 0; k0 < K; k0 += 64) {
        __syncthreads();
#pragma unroll
        for (int j = 0; j < AI; ++j) {
            int r0 = (w * AI + j) * 8;
            gload_lds16(Ag + (size_t)r0 * ldA + k0, As + r0 * 64 + lane * 8);
        }
#pragma unroll
        for (int j = 0; j < 4; ++j) {
            int r0 = (w * 4 + j) * 8;
            gload_lds16(Bg + (size_t)r0 * ldB + k0, Bs + r0 * 64 + lane * 8);
        }
        __syncthreads();
#pragma unroll
        for (int kk = 0; kk < 64; kk += 32) {
            const int pc = ((((kk >> 3) + (lane >> 4)) ^ fx) << 3);
            bf16x8 af[AI], bfr[4];
#pragma unroll
            for (int i = 0; i < AI; ++i)
                af[i] = *(const bf16x8*)(As + (wm + i * 16 + fr) * 64 + pc);
#pragma unroll
            for (int j = 0; j < 4; ++j)
                bfr[j] = *(const bf16x8*)(Bs + (wn + j * 16 + fr) * 64 + pc);
#pragma unroll
            for (int i = 0; i < AI; ++i)
#pragma unroll
                for (int j = 0; j < 4; ++j)
                    acc[i][j] = __builtin_amdgcn_mfma_f32_16x16x32_bf16(af[i], bfr[j], acc[i][j], 0, 0, 0);
        }
    }

    // Epilogue. C/D layout: col = lane&15, row = (lane>>4)*4 + reg.
    const int crow = (lane >> 4) * 4;
    const int ccol = lane & 15;
    const int nn   = n0 + wn;

    if (zout) {
        // Pure GEMM + bias -> f32 gate pre-activations (decoder Z precompute).
        float bi[4];
#pragma unroll
        for (int j = 0; j < 4; ++j) bi[j] = bias[nn + j * 16 + ccol];
#pragma unroll
        for (int i = 0; i < AI; ++i) {
#pragma unroll
            for (int r = 0; r < 4; ++r) {
                int t = m0 + wm + i * 16 + crow + r;
                float* zr = zout + (size_t)t * ldZ + nn + ccol;
#pragma unroll
                for (int j = 0; j < 4; ++j) zr[j * 16] = acc[i][j][r] + bi[j];
            }
        }
        return;
    }

    const int e = (nn >> 2) + ccol;
    float bi[4];
    if (!zp) {
#pragma unroll
        for (int j = 0; j < 4; ++j) bi[j] = bias[nn + j * 16 + ccol];
    }

#pragma unroll
    for (int i = 0; i < AI; ++i) {
#pragma unroll
        for (int r = 0; r < 4; ++r) {
            int t = m0 + wm + i * 16 + crow + r;
            float g0, g1, g2, g3;
            if (zp) {
                const float* zr = zp + (size_t)t * ldZ + nn + ccol;
                g0 = acc[i][0][r] + zr[0];
                g1 = acc[i][1][r] + zr[16];
                g2 = acc[i][2][r] + zr[32];
                g3 = acc[i][3][r] + zr[48];
            } else {
                g0 = acc[i][0][r] + bi[0];
                g1 = acc[i][1][r] + bi[1];
                g2 = acc[i][2][r] + bi[2];
                g3 = acc[i][3][r] + bi[3];
            }
            size_t cix = (size_t)t * EP + e;
            float cold = 0.0f;
            if (!czero) cold = c[cix];
            float cv = sigf(g1) * cold + sigf(g0) * tanhfast(g2);
            c[cix] = cv;
            float hv = sigf(g3) * tanhfast(cv);
            if (relu) hv = fmaxf(hv, 0.0f);
            if (hb) hb[(size_t)t * ldH + hoff + e] = (bf16_t)hv;
            else    hf[(size_t)t * EP + e] = hv;
        }
    }
}

// ---------------- Packing (interleaved-gate layout, vectorized) ----------------
// A_enc (4096 x 1152 bf16): [x(0:101) pad(101:128) h(128:1152)]
// A_dec (4096 x 1152 bf16): [enc(0:1024) h(1024:1152)]
// One kernel, block-range dispatched (all outputs disjoint):
//   [0,     9216) : W_enc  (16384 rows * 144 groups of 8)
//   [9216, 11520) : A_enc x+zero fill (4096 rows * 144 groups)
//   [11520,12672) : W_dec  (2048 rows * 144 groups)
//   [12672,12744) : biases (16384 enc + 2048 dec)
// Layer-0 K-trim + czero keep every other buffer write-before-read
// (ws re-poisoned 0xAA every call).
__global__ void pack_all(const float* __restrict__ x,
                         const float* __restrict__ eWih, const float* __restrict__ eWhh,
                         const float* __restrict__ ebih, const float* __restrict__ ebhh,
                         const float* __restrict__ dWih, const float* __restrict__ dWhh,
                         const float* __restrict__ dbih, const float* __restrict__ dbhh,
                         bf16_t* __restrict__ Aenc, bf16_t* __restrict__ Wenc,
                         bf16_t* __restrict__ Wdec,
                         float* __restrict__ bse, float* __restrict__ bsd)
{
    const int b = blockIdx.x;
    if (b < 9216) {
        int gid = b * 256 + threadIdx.x;
        int row = gid / 144, grp = gid - row * 144;
        int l = row >> 12, p = row & 4095;
        int g = (p >> 4) & 3, e = ((p >> 6) << 4) + (p & 15);
        int c0 = grp * 8;
        float v[8];
#pragma unroll
        for (int u = 0; u < 8; ++u) v[u] = 0.0f;
        if (e < 1000) {
            size_t r = (size_t)l * 4000 + g * 1000 + e;
            if (c0 >= 128 && c0 < 1128) {
                const float* src = eWhh + r * 1000 + (c0 - 128);
                float4 a = *(const float4*)src;
                float4 bq = *(const float4*)(src + 4);
                v[0]=a.x; v[1]=a.y; v[2]=a.z; v[3]=a.w; v[4]=bq.x; v[5]=bq.y; v[6]=bq.z; v[7]=bq.w;
            } else if (c0 < 128) {
                const float* src = eWih + r * 101;
#pragma unroll
                for (int u = 0; u < 8; ++u) { int cc = c0 + u; if (cc < 101) v[u] = src[cc]; }
            }
        }
        bf16x8 o;
#pragma unroll
        for (int u = 0; u < 8; ++u) o[u] = (bf16_t)v[u];
        *(bf16x8*)(Wenc + (size_t)row * 1152 + c0) = o;
    } else if (b < 11520) {
        int gid = (b - 9216) * 256 + threadIdx.x;
        int row = gid / 144, grp = gid - row * 144;
        int c0  = grp * 8;
        float v[8];
#pragma unroll
        for (int u = 0; u < 8; ++u) v[u] = 0.0f;
        if (c0 < 101) {
            const float* src = x + (size_t)row * 101;
#pragma unroll
            for (int u = 0; u < 8; ++u) { int cc = c0 + u; if (cc < 101) v[u] = src[cc]; }
        }
        bf16x8 o;
#pragma unroll
        for (int u = 0; u < 8; ++u) o[u] = (bf16_t)v[u];
        *(bf16x8*)(Aenc + (size_t)row * 1152 + c0) = o;
    } else if (b < 12672) {
        int gid = (b - 11520) * 256 + threadIdx.x;
        int row = gid / 144, grp = gid - row * 144;
        int l = row >> 9, p = row & 511;
        int g = (p >> 4) & 3, e = ((p >> 6) << 4) + (p & 15);
        int c0 = grp * 8;
        float v[8];
#pragma unroll
        for (int u = 0; u < 8; ++u) v[u] = 0.0f;
        if (e < 101) {
            size_t r = (size_t)l * 404 + g * 101 + e;
            if (c0 < 1000) {
                const float* src = dWih + r * 1000 + c0;
                float4 a = *(const float4*)src;
                float4 bq = *(const float4*)(src + 4);
                v[0]=a.x; v[1]=a.y; v[2]=a.z; v[3]=a.w; v[4]=bq.x; v[5]=bq.y; v[6]=bq.z; v[7]=bq.w;
            } else if (c0 >= 1024 && c0 < 1128) {
                const float* src = dWhh + r * 101;
#pragma unroll
                for (int u = 0; u < 8; ++u) { int cc = c0 + u; if (cc < 1125) v[u] = src[cc - 1024]; }
            }
        }
        bf16x8 o;
#pragma unroll
        for (int u = 0; u < 8; ++u) o[u] = (bf16_t)v[u];
        *(bf16x8*)(Wdec + (size_t)row * 1152 + c0) = o;
    } else {
        int idx = (b - 12672) * 256 + threadIdx.x;
        if (idx < 16384) {
            int l = idx >> 12, p = idx & 4095;
            int g = (p >> 4) & 3, e = ((p >> 6) << 4) + (p & 15);
            bse[idx] = (e < 1000) ? (ebih[l * 4000 + g * 1000 + e] + ebhh[l * 4000 + g * 1000 + e]) : 0.0f;
        } else {
            int k = idx - 16384;
            int l = k >> 9, p = k & 511;
            int g = (p >> 4) & 3, e = ((p >> 6) << 4) + (p & 15);
            bsd[k] = (e < 101) ? (dbih[l * 404 + g * 101 + e] + dbhh[l * 404 + g * 101 + e]) : 0.0f;
        }
    }
}

// ---------------- log_softmax over 101 valid cols (stride 128) ----------------
__global__ void log_softmax_k(const float* __restrict__ h, float* __restrict__ out)
{
    int row = blockIdx.x;
    int l   = threadIdx.x;          // 64
    const float* hr = h + (size_t)row * 128;
    float v1 = (l < 101)      ? hr[l]      : -INFINITY;
    float v2 = (l + 64 < 101) ? hr[l + 64] : -INFINITY;
    float m = fmaxf(v1, v2);
#pragma unroll
    for (int off = 32; off > 0; off >>= 1) m = fmaxf(m, __shfl_down(m, off));
    m = __shfl(m, 0);
    float ev = ((l < 101) ? __expf(v1 - m) : 0.0f) + ((l + 64 < 101) ? __expf(v2 - m) : 0.0f);
#pragma unroll
    for (int off = 32; off > 0; off >>= 1) ev += __shfl_down(ev, off);
    float lse = m + __logf(__shfl(ev, 0));
    float* orow = out + (size_t)row * 101;
    if (l < 101)      orow[l]      = v1 - lse;
    if (l + 64 < 101) orow[l + 64] = v2 - lse;
}

extern "C" void kernel_launch(void* const* d_in, const int* in_sizes, int n_in,
                              void* d_out, int out_size, void* d_ws, size_t ws_size,
                              hipStream_t stream)
{
    (void)in_sizes; (void)n_in; (void)out_size; (void)ws_size;
    const float* x    = (const float*)d_in[0];
    const float* eWih = (const float*)d_in[1];
    const float* eWhh = (const float*)d_in[2];
    const float* ebih = (const float*)d_in[3];
    const float* ebhh = (const float*)d_in[4];
    const float* dWih = (const float*)d_in[5];
    const float* dWhh = (const float*)d_in[6];
    const float* dbih = (const float*)d_in[7];
    const float* dbhh = (const float*)d_in[8];

    char* ws = (char*)d_ws;
    bf16_t* Aenc = (bf16_t*)(ws);                 // 4096*1152*2   =  9,437,184
    bf16_t* Wenc = (bf16_t*)(ws + 9437184);       // 4*4096*1152*2 = 37,748,736
    bf16_t* Adec = (bf16_t*)(ws + 47185920);      //                  9,437,184
    bf16_t* Wdec = (bf16_t*)(ws + 56623104);      // 4*512*1152*2  =  4,718,592
    float*  bse  = (float*) (ws + 61341696);      // 4*4096*4      =     65,536
    float*  bsd  = (float*) (ws + 61407232);      // 4*512*4       =      8,192
    float*  cenc = (float*) (ws + 61415424);      // 4096*1024*4   = 16,777,216
    float*  cdec = (float*) (ws + 78192640);      // 4096*128*4    =   2,097,152
    float*  hdec = (float*) (ws + 80289792);      // 4096*128*4    =   2,097,152  (end 82,386,944)
    // Z (decoder gate precompute, 4096 x 2048 f32 = 33,554,432 B) aliases the
    // Wenc region (37.7 MB), which is dead after encoder layer 3 reads it.
    float*  Z    = (float*)(ws + 9437184);

    pack_all<<<12744, 256, 0, stream>>>(x, eWih, eWhh, ebih, ebhh, dWih, dWhh, dbih, dbhh,
                                        Aenc, Wenc, Wdec, bse, bsd);

    // Encoder: 4 layers, 2-barrier BM=128 kernel (grid 32x32 = 1024 blocks,
    // 4 blocks/CU). Layer 0: h == 0 -> K=128 (x part only), czero=1.
    for (int l = 0; l < 4; ++l) {
        gemm_lstm<128><<<dim3(32, 32), 256, 0, stream>>>(
            Aenc, Wenc + (size_t)l * 4096 * 1152, bse + l * 4096,
            nullptr, nullptr, 0,
            cenc, 1024,
            (l < 3) ? Aenc : Adec, 1152, (l < 3) ? 128 : 0, nullptr,
            (l == 0) ? 128 : 1152, 1152, 1152, (l == 3) ? 1 : 0, (l == 0) ? 1 : 0);
    }

    // Decoder algebraic split: every decoder layer's input is the SAME enc
    // vector, so the enc@dWih_l^T + b term (K=1024, 89% of decoder FLOPs,
    // no serial dependency) is hoisted into ONE well-shaped GEMM:
    //   Z[t, l*512+p] = enc @ dWih^T + b   (M=4096, N=2048, K=1024)
    // grid(16,32) = 512 blocks = 2 blocks/CU. Then each decoder layer is only
    // the recurrent h@dWhh part (K=128; layer 0 is K=0 since h=0).
    gemm_lstm<128><<<dim3(16, 32), 256, 0, stream>>>(
        Adec, Wdec, bsd,
        nullptr, Z, 2048,
        nullptr, 0,
        nullptr, 0, 0, nullptr,
        1024, 1152, 1152, 0, 0);

    // Decoder recurrent chain: grid(4,128) = 512 blocks, BM=32.
    // Layer 0: gates == Z_0 exactly (h=0) -> K=0 skips the GEMM, czero=1.
    for (int l = 0; l < 4; ++l) {
        gemm_lstm<32><<<dim3(4, 128), 256, 0, stream>>>(
            Adec + 1024, Wdec + 1024, bsd + l * 512,
            Z + l * 512, nullptr, 2048,
            cdec, 128,
            (l < 3) ? Adec : nullptr, 1152, 1024, (l == 3) ? hdec : nullptr,
            (l == 0) ? 0 : 128, 1152, 1152, 0, (l == 0) ? 1 : 0);
    }
    log_softmax_k<<<4096, 64, 0, stream>>>(hdec, (float*)d_out);
}